// Round 12
// baseline (724.925 us; speedup 1.0000x reference)
//
#include <hip/hip_runtime.h>
#include <hip/hip_bf16.h>
#include <stdint.h>

typedef __bf16 bf16x8 __attribute__((ext_vector_type(8)));
typedef float f32x4 __attribute__((ext_vector_type(4)));
typedef unsigned short ushort8v __attribute__((ext_vector_type(8)));

// Problem constants
#define NB    16
#define CIN   256
#define COUT  256
#define HH    128
#define WW    128

// ws layout (bytes)
#define OFF_ZROW  0u                    // 65536 zeroed page (one fake xT row)
#define OFF_COFF  (1u << 16)            // 2*16*256 f32 = 8 KB
#define OFF_TMPS  (1u << 17)            // 16*16*768 f32 = 768 KB
#define OFF_WEFF  (1u << 20)            // 16*9*256*256 bf16 = 18 MB
#define OFF_XT    (20u * 1024u * 1024u) // G * 8 MB bf16 channels-last x
#define XT_PER_B  (128u * 128u * 256u * 2u)

__device__ inline void gload16(const void* g, void* l) {
  __builtin_amdgcn_global_load_lds(
      (const __attribute__((address_space(1))) void*)g,
      (__attribute__((address_space(3))) void*)l, 16, 0, 0);
}

__device__ inline ushort f2bf(float f) {
  __hip_bfloat16 h = __float2bfloat16(f);
  union { __hip_bfloat16 b; ushort u; } cv;
  cv.b = h;
  return cv.u;
}

// ---------------- kernel 1: embed MLP -> coff[2][16][16][16] ----------------
__global__ void k_coff(const float* __restrict__ wms,
                       const float* __restrict__ w1a, const float* __restrict__ b1a,
                       const float* __restrict__ w2a, const float* __restrict__ b2a,
                       const float* __restrict__ w1b, const float* __restrict__ b1b,
                       const float* __restrict__ w2b, const float* __restrict__ b2b,
                       float* __restrict__ coff) {
  int br = blockIdx.x >> 4, b = blockIdx.x & 15;
  const float* w1 = br ? w1b : w1a;
  const float* b1 = br ? b1b : b1a;
  const float* w2 = br ? w2b : w2a;
  const float* b2 = br ? b2b : b2a;
  const float* v = wms + (br * 16 + b) * 32;
  __shared__ float h[128];
  int t = threadIdx.x;
  if (t < 128) {
    float a = b1[t];
#pragma unroll
    for (int i = 0; i < 32; ++i) a += w1[t * 32 + i] * v[i];
    h[t] = a >= 0.f ? a : 0.2f * a;
  }
  __syncthreads();
  float a = b2[t];
  for (int j = 0; j < 128; ++j) a += w2[t * 128 + j] * h[j];
  coff[(br * 16 + b) * 256 + t] = a;
}

// ------------- kernel 2a: tmpS[b][r][c] = coff1@A1 + coff2@A2 ---------------
__global__ void k_tmps(const float* __restrict__ coff,
                       const float* __restrict__ A1, const float* __restrict__ A2,
                       float* __restrict__ tmpS) {
  int b = blockIdx.x >> 4, r = blockIdx.x & 15;
  __shared__ float c1[16], c2[16];
  int t = threadIdx.x;
  if (t < 16) {
    c1[t] = coff[b * 256 + r * 16 + t];
    c2[t] = coff[(16 + b) * 256 + r * 16 + t];
  }
  __syncthreads();
  for (int c = t; c < 768; c += 256) {
    float s = 0.f;
#pragma unroll
    for (int q = 0; q < 16; ++q) s += c1[q] * A1[q * 768 + c] + c2[q] * A2[q * 768 + c];
    tmpS[(b * 16 + r) * 768 + c] = s;
  }
}

// ------- kernel 2b: Weff[b][tt][co][ci] = conv_w + loraB @ tmpS (bf16) -------
__global__ __launch_bounds__(256) void k_weff(const float* __restrict__ conv_w,
                                              const float* __restrict__ loraB,
                                              const float* __restrict__ tmpS,
                                              __hip_bfloat16* __restrict__ Weff) {
  int bid = blockIdx.x;
  int co = bid & 255, b = bid >> 8;
  int t = threadIdx.x;
  __shared__ float Bs[3][16];
  __shared__ ushort obuf[2304];
  if (t < 48) Bs[t >> 4][t & 15] = loraB[(co * 3 + (t >> 4)) * 16 + (t & 15)];
  __syncthreads();
  const float* T = tmpS + (size_t)b * 16 * 768;
  const float* W = conv_w + (size_t)co * 2304;
#pragma unroll
  for (int k = 0; k < 3; ++k) {
#pragma unroll
    for (int cc = 0; cc < 3; ++cc) {
      int c = cc * 256 + t;
      float s = W[k * 768 + c];
#pragma unroll
      for (int r = 0; r < 16; ++r) s += Bs[k][r] * T[r * 768 + c];
      int f = k * 768 + c;  // local flat over (ci,kh,kw) for this co
      int ci = f / 9, tt = f - ci * 9;
      obuf[tt * 256 + ci] = f2bf(s);
    }
  }
  __syncthreads();
#pragma unroll
  for (int tt = 0; tt < 9; ++tt)
    ((ushort*)Weff)[((size_t)(b * 9 + tt) * 256 + co) * 256 + t] = obuf[tt * 256 + t];
}

// -------- kernel 3: x (f32, NCHW) -> xT (bf16, N H W C channels-last) --------
__global__ __launch_bounds__(256) void k_xt(const float* __restrict__ x,
                                            __hip_bfloat16* __restrict__ xT, int b0) {
  __shared__ ushort t[32][132];
  int bid = blockIdx.x;
  int cb = bid & 7, h = (bid >> 3) & 127, bp = bid >> 10;
  int b = b0 + bp;
  int tid = threadIdx.x;
  int ci2 = tid >> 5, w4 = (tid & 31) * 4;
  const float* srcb = x + ((size_t)(b * 256 + cb * 32) * 128 + h) * 128;
#pragma unroll
  for (int k = 0; k < 4; ++k) {
    int c = ci2 + k * 8;
    float4 v = *(const float4*)(srcb + (size_t)c * 16384 + w4);
    ushort4 u;
    u.x = f2bf(v.x);
    u.y = f2bf(v.y);
    u.z = f2bf(v.z);
    u.w = f2bf(v.w);
    *(ushort4*)&t[c][w4] = u;
  }
  __syncthreads();
  int w = tid >> 1, hf = tid & 1;
  ushort8v o0, o1;
#pragma unroll
  for (int j = 0; j < 8; ++j) {
    o0[j] = t[hf * 16 + j][w];
    o1[j] = t[hf * 16 + 8 + j][w];
  }
  ushort* dst = (ushort*)xT + (size_t)bp * 128 * 128 * 256 +
                ((size_t)h * 128 + w) * 256 + cb * 32 + hf * 16;
  *(ushort8v*)dst = o0;
  *(ushort8v*)(dst + 8) = o1;
}

// ------------------- kernel 4: per-sample implicit-GEMM conv ------------------
// A-IN-REGISTERS structure: Weff A-frags loaded global->VGPR per wave (L2-
// resident half-slab), double-buffered per kh (aA/aB, static indexing), issued
// one kh-phase (~1000 cyc) ahead; compiler places the vmcnt waits. No W LDS,
// no W barriers. Only x lives in LDS, DOUBLE-buffered (2 x 25 KB): stage
// chunk c+1 during chunk c, ONE __syncthreads per chunk (8 total vs 48).
// Tile 128co x 128px, 4 waves of 64co x 64px, 2 blocks/CU.
// xs granule swizzle g' = g ^ ((row>>1)&3) unchanged (proven 0-conflict).
__global__ __launch_bounds__(256, 2) void k_conv(
    const __hip_bfloat16* __restrict__ xT,
    const __hip_bfloat16* __restrict__ Weff,
    const __hip_bfloat16* __restrict__ zrow,
    const float* __restrict__ cbias,
    float* __restrict__ out, int b0) {
  // xs[buf][ri][wi][ci] : ri 0..2 -> x row h0-1+ri ; wi 0..129 ; 32 ci
  __shared__ __align__(16) __hip_bfloat16 xs[2 * 3 * 130 * 32];  // 49,920 B

  // XCD-aware swizzle (nwg = G*256, always % 8 == 0)
  int nwg = gridDim.x;
  int bid0 = blockIdx.x;
  int bid = (bid0 & 7) * (nwg >> 3) + (bid0 >> 3);

  int h0 = bid & 127, coh = (bid >> 7) & 1, bp = bid >> 8;
  int b = b0 + bp;

  int tid = threadIdx.x;
  int wid = tid >> 6, lane = tid & 63;
  int l15 = lane & 15, lh = lane >> 4;
  int wm = wid >> 1;                // co quarter within half (0/1) -> 64 co
  int w0 = (wid & 1) * 64;          // w half
  int lrow = lane >> 2;
  int sgx = (lane & 3) ^ (((1 + lrow) >> 1) & 3);  // x-stage source granule

  // zero the w-pad columns of BOTH buffers; never overwritten after
#pragma unroll
  for (int bufi = 0; bufi < 2; ++bufi)
    if (tid < 192) {
      int ri = tid >> 6, which = (tid >> 5) & 1, ci = tid & 31;
      ((ushort*)xs)[bufi * 12480 + ri * 4160 + (which ? 129 : 0) * 32 + ci] = 0;
    }

  // ---- precomputed offsets (elements) ----
  int b_base0 = (w0 + l15 + 0) * 32 + ((lh ^ (((l15 + 0) >> 1) & 3)) * 8);
  int b_base1 = (w0 + l15 + 1) * 32 + ((lh ^ (((l15 + 1) >> 1) & 3)) * 8);
  int b_base2 = (w0 + l15 + 2) * 32 + ((lh ^ (((l15 + 2) >> 1) & 3)) * 8);
  int xoff = lrow * 256 + sgx * 8;               // + wblk*4096 + c0

  const __hip_bfloat16* xTb = xT + (size_t)bp * 128 * 128 * 256;
  const __hip_bfloat16* r0 = (h0 > 0)   ? xTb + (size_t)(h0 - 1) * 32768 : zrow;
  const __hip_bfloat16* r1 = xTb + (size_t)h0 * 32768;
  const __hip_bfloat16* r2 = (h0 < 127) ? xTb + (size_t)(h0 + 1) * 32768 : zrow;
  // per-lane A base: co-row (coh*128 + wm*64 + l15), k-offset lh*8
  const __hip_bfloat16* wAb =
      Weff + ((size_t)(b * 9) << 16) + (coh * 128 + wm * 64 + l15) * 256 + lh * 8;

  f32x4 acc[4][4];
#pragma unroll
  for (int mf = 0; mf < 4; ++mf)
#pragma unroll
    for (int nf = 0; nf < 4; ++nf) acc[mf][nf] = (f32x4){0.f, 0.f, 0.f, 0.f};

// load one kh's 12 A-frags (global -> regs, 16B/lane each, L2-resident)
#define LOAD_A(DST, KH)                                                        \
  {                                                                            \
    const __hip_bfloat16* wt = wAb + (((size_t)(KH) * 3) << 16) + c0;          \
    _Pragma("unroll")                                                          \
    for (int kw = 0; kw < 3; ++kw)                                             \
      _Pragma("unroll")                                                        \
      for (int mf = 0; mf < 4; ++mf)                                           \
        DST[kw * 4 + mf] = *(const bf16x8*)(wt + kw * 65536 + mf * 4096);      \
  }

// compute one kh (B-frags from xsb, A from regs); 12 ds_read + 48 MFMA
#define COMPUTE_KH(KH, AR)                                                     \
  {                                                                            \
    _Pragma("unroll")                                                          \
    for (int kw = 0; kw < 3; ++kw) {                                           \
      const int bb = (kw == 0) ? b_base0 : ((kw == 1) ? b_base1 : b_base2);    \
      bf16x8 bfr[4];                                                           \
      _Pragma("unroll")                                                        \
      for (int nf = 0; nf < 4; ++nf)                                           \
        bfr[nf] = *(const bf16x8*)&xsb[(KH) * 4160 + bb + nf * 512];           \
      _Pragma("unroll")                                                        \
      for (int mf = 0; mf < 4; ++mf)                                           \
        _Pragma("unroll")                                                      \
        for (int nf = 0; nf < 4; ++nf)                                         \
          acc[mf][nf] = __builtin_amdgcn_mfma_f32_16x16x32_bf16(               \
              AR[kw * 4 + mf], bfr[nf], acc[mf][nf], 0, 0, 0);                 \
    }                                                                          \
  }

// stage x rows for chunk CN into buffer (CN&1)
#define STAGE_X(CN)                                                            \
  {                                                                            \
    __hip_bfloat16* xd = xs + ((CN) & 1) * 12480;                              \
    int cs = (CN) * 32;                                                        \
    _Pragma("unroll")                                                          \
    for (int k = 0; k < 6; ++k) {                                              \
      const int ri = k >> 1;                                                   \
      int wblk = (k & 1) * 4 + wid;                                            \
      const __hip_bfloat16* rp = (ri == 0) ? r0 : ((ri == 1) ? r1 : r2);       \
      gload16((const void*)(rp + wblk * 4096 + cs + xoff),                     \
              (void*)(xd + ri * 4160 + (1 + wblk * 16) * 32));                 \
    }                                                                          \
  }

  // prologue: stage chunk 0; drain (also publishes pads)
  STAGE_X(0);
  __syncthreads();

  bf16x8 aA[12], aB[12];

#pragma unroll 1
  for (int c = 0; c < 8; ++c) {
    const __hip_bfloat16* xsb = xs + (c & 1) * 12480;
    int c0 = c * 32;

    LOAD_A(aA, 0);            // kh0 A (wait inserted before first MFMA use)
    LOAD_A(aB, 1);            // kh1 A, ~1 phase of cover
    if (c < 7) STAGE_X(c + 1);  // x for next chunk into other buffer

    COMPUTE_KH(0, aA);
    LOAD_A(aA, 2);            // kh2 A, issued behind kh1 compute
    COMPUTE_KH(1, aB);
    COMPUTE_KH(2, aA);

    __syncthreads();          // drains x(c+1) (issued ~2 phases ago) and
                              // fences xs buffer reuse
  }
#undef LOAD_A
#undef COMPUTE_KH
#undef STAGE_X

  // epilogue: D[m][n]: m(co) = (lane>>4)*4 + r, n(px) = lane&15
#pragma unroll
  for (int mf = 0; mf < 4; ++mf) {
    int cobase = coh * 128 + wm * 64 + mf * 16 + lh * 4;
#pragma unroll
    for (int r = 0; r < 4; ++r) {
      int co = cobase + r;
      float bias = cbias[co];
      size_t obase = ((size_t)(b * 256 + co) * 128 + h0) * 128 + w0 + l15;
#pragma unroll
      for (int nf = 0; nf < 4; ++nf) out[obase + nf * 16] = acc[mf][nf][r] + bias;
    }
  }
}

extern "C" void kernel_launch(void* const* d_in, const int* in_sizes, int n_in,
                              void* d_out, int out_size, void* d_ws, size_t ws_size,
                              hipStream_t stream) {
  const float* x      = (const float*)d_in[0];
  const float* wms    = (const float*)d_in[1];
  const float* conv_w = (const float*)d_in[2];
  const float* conv_b = (const float*)d_in[3];
  const float* e1w1   = (const float*)d_in[4];
  const float* e1b1   = (const float*)d_in[5];
  const float* e1w2   = (const float*)d_in[6];
  const float* e1b2   = (const float*)d_in[7];
  const float* e2w1   = (const float*)d_in[8];
  const float* e2b1   = (const float*)d_in[9];
  const float* e2w2   = (const float*)d_in[10];
  const float* e2b2   = (const float*)d_in[11];
  const float* A1     = (const float*)d_in[12];
  const float* A2     = (const float*)d_in[13];
  const float* loraB  = (const float*)d_in[14];
  float* out = (float*)d_out;

  uint8_t* ws = (uint8_t*)d_ws;
  __hip_bfloat16* zrow = (__hip_bfloat16*)(ws + OFF_ZROW);
  float* coff          = (float*)(ws + OFF_COFF);
  float* tmpS          = (float*)(ws + OFF_TMPS);
  __hip_bfloat16* Weff = (__hip_bfloat16*)(ws + OFF_WEFF);
  __hip_bfloat16* xT   = (__hip_bfloat16*)(ws + OFF_XT);

  // group size: how many samples' xT fit in ws
  int G = 16;
  while (G > 1 && (size_t)OFF_XT + (size_t)G * XT_PER_B > ws_size) G >>= 1;

  hipMemsetAsync(zrow, 0, 65536, stream);
  k_coff<<<32, 256, 0, stream>>>(wms, e1w1, e1b1, e1w2, e1b2, e2w1, e2b1, e2w2, e2b2, coff);
  k_tmps<<<256, 256, 0, stream>>>(coff, A1, A2, tmpS);
  k_weff<<<16 * 256, 256, 0, stream>>>(conv_w, loraB, tmpS, Weff);
  for (int g = 0; g < 16; g += G) {
    k_xt<<<G * 1024, 256, 0, stream>>>(x, xT, g);
    k_conv<<<G * 256, 256, 0, stream>>>(xT, Weff, zrow, conv_b, out, g);
  }
}

// Round 13
// 422.864 us; speedup vs baseline: 1.7143x; 1.7143x over previous
//
#include <hip/hip_runtime.h>
#include <hip/hip_bf16.h>
#include <stdint.h>

typedef __bf16 bf16x8 __attribute__((ext_vector_type(8)));
typedef float f32x4 __attribute__((ext_vector_type(4)));
typedef unsigned short ushort8v __attribute__((ext_vector_type(8)));

// Problem constants
#define NB    16
#define CIN   256
#define COUT  256
#define HH    128
#define WW    128

// ws layout (bytes)
#define OFF_ZROW  0u                    // 65536 zeroed page (one fake xT row)
#define OFF_COFF  (1u << 16)            // 2*16*256 f32 = 8 KB
#define OFF_TMPS  (1u << 17)            // 16*16*768 f32 = 768 KB
#define OFF_WEFF  (1u << 20)            // 16*9*256*256 bf16 = 18 MB
#define OFF_XT    (20u * 1024u * 1024u) // G * 8 MB bf16 channels-last x
#define XT_PER_B  (128u * 128u * 256u * 2u)

__device__ inline void gload16(const void* g, void* l) {
  __builtin_amdgcn_global_load_lds(
      (const __attribute__((address_space(1))) void*)g,
      (__attribute__((address_space(3))) void*)l, 16, 0, 0);
}

__device__ inline ushort f2bf(float f) {
  __hip_bfloat16 h = __float2bfloat16(f);
  union { __hip_bfloat16 b; ushort u; } cv;
  cv.b = h;
  return cv.u;
}

// ---------------- kernel 1: embed MLP -> coff[2][16][16][16] ----------------
__global__ void k_coff(const float* __restrict__ wms,
                       const float* __restrict__ w1a, const float* __restrict__ b1a,
                       const float* __restrict__ w2a, const float* __restrict__ b2a,
                       const float* __restrict__ w1b, const float* __restrict__ b1b,
                       const float* __restrict__ w2b, const float* __restrict__ b2b,
                       float* __restrict__ coff) {
  int br = blockIdx.x >> 4, b = blockIdx.x & 15;
  const float* w1 = br ? w1b : w1a;
  const float* b1 = br ? b1b : b1a;
  const float* w2 = br ? w2b : w2a;
  const float* b2 = br ? b2b : b2a;
  const float* v = wms + (br * 16 + b) * 32;
  __shared__ float h[128];
  int t = threadIdx.x;
  if (t < 128) {
    float a = b1[t];
#pragma unroll
    for (int i = 0; i < 32; ++i) a += w1[t * 32 + i] * v[i];
    h[t] = a >= 0.f ? a : 0.2f * a;
  }
  __syncthreads();
  float a = b2[t];
  for (int j = 0; j < 128; ++j) a += w2[t * 128 + j] * h[j];
  coff[(br * 16 + b) * 256 + t] = a;
}

// ------------- kernel 2a: tmpS[b][r][c] = coff1@A1 + coff2@A2 ---------------
__global__ void k_tmps(const float* __restrict__ coff,
                       const float* __restrict__ A1, const float* __restrict__ A2,
                       float* __restrict__ tmpS) {
  int b = blockIdx.x >> 4, r = blockIdx.x & 15;
  __shared__ float c1[16], c2[16];
  int t = threadIdx.x;
  if (t < 16) {
    c1[t] = coff[b * 256 + r * 16 + t];
    c2[t] = coff[(16 + b) * 256 + r * 16 + t];
  }
  __syncthreads();
  for (int c = t; c < 768; c += 256) {
    float s = 0.f;
#pragma unroll
    for (int q = 0; q < 16; ++q) s += c1[q] * A1[q * 768 + c] + c2[q] * A2[q * 768 + c];
    tmpS[(b * 16 + r) * 768 + c] = s;
  }
}

// ------- kernel 2b: Weff[b][tt][co][ci] = conv_w + loraB @ tmpS (bf16) -------
__global__ __launch_bounds__(256) void k_weff(const float* __restrict__ conv_w,
                                              const float* __restrict__ loraB,
                                              const float* __restrict__ tmpS,
                                              __hip_bfloat16* __restrict__ Weff) {
  int bid = blockIdx.x;
  int co = bid & 255, b = bid >> 8;
  int t = threadIdx.x;
  __shared__ float Bs[3][16];
  __shared__ ushort obuf[2304];
  if (t < 48) Bs[t >> 4][t & 15] = loraB[(co * 3 + (t >> 4)) * 16 + (t & 15)];
  __syncthreads();
  const float* T = tmpS + (size_t)b * 16 * 768;
  const float* W = conv_w + (size_t)co * 2304;
#pragma unroll
  for (int k = 0; k < 3; ++k) {
#pragma unroll
    for (int cc = 0; cc < 3; ++cc) {
      int c = cc * 256 + t;
      float s = W[k * 768 + c];
#pragma unroll
      for (int r = 0; r < 16; ++r) s += Bs[k][r] * T[r * 768 + c];
      int f = k * 768 + c;  // local flat over (ci,kh,kw) for this co
      int ci = f / 9, tt = f - ci * 9;
      obuf[tt * 256 + ci] = f2bf(s);
    }
  }
  __syncthreads();
#pragma unroll
  for (int tt = 0; tt < 9; ++tt)
    ((ushort*)Weff)[((size_t)(b * 9 + tt) * 256 + co) * 256 + t] = obuf[tt * 256 + t];
}

// -------- kernel 3: x (f32, NCHW) -> xT (bf16, N H W C channels-last) --------
__global__ __launch_bounds__(256) void k_xt(const float* __restrict__ x,
                                            __hip_bfloat16* __restrict__ xT, int b0) {
  __shared__ ushort t[32][132];
  int bid = blockIdx.x;
  int cb = bid & 7, h = (bid >> 3) & 127, bp = bid >> 10;
  int b = b0 + bp;
  int tid = threadIdx.x;
  int ci2 = tid >> 5, w4 = (tid & 31) * 4;
  const float* srcb = x + ((size_t)(b * 256 + cb * 32) * 128 + h) * 128;
#pragma unroll
  for (int k = 0; k < 4; ++k) {
    int c = ci2 + k * 8;
    float4 v = *(const float4*)(srcb + (size_t)c * 16384 + w4);
    ushort4 u;
    u.x = f2bf(v.x);
    u.y = f2bf(v.y);
    u.z = f2bf(v.z);
    u.w = f2bf(v.w);
    *(ushort4*)&t[c][w4] = u;
  }
  __syncthreads();
  int w = tid >> 1, hf = tid & 1;
  ushort8v o0, o1;
#pragma unroll
  for (int j = 0; j < 8; ++j) {
    o0[j] = t[hf * 16 + j][w];
    o1[j] = t[hf * 16 + 8 + j][w];
  }
  ushort* dst = (ushort*)xT + (size_t)bp * 128 * 128 * 256 +
                ((size_t)h * 128 + w) * 256 + cb * 32 + hf * 16;
  *(ushort8v*)dst = o0;
  *(ushort8v*)(dst + 8) = o1;
}

// ------------------- kernel 4: per-sample implicit-GEMM conv ------------------
// R10's proven schedule with a 2-ROW block tile: 128co x 2rows x 128w, 4 waves
// of 128co x 64w x 1row (acc = 128 AGPR). Halves the generation count and
// doubles MFMA work per fixed per-chunk overhead (syncs/drains); x-halo reuse
// improves (4 input rows -> 2 output rows). LDS 57.9 KB -> 2 blocks/CU.
// Staging patterns + granule swizzle g' = g ^ ((row>>1)&3): identical to R10
// (measured 0 bank conflicts).
__global__ __launch_bounds__(256, 2) void k_conv(
    const __hip_bfloat16* __restrict__ xT,
    const __hip_bfloat16* __restrict__ Weff,
    const __hip_bfloat16* __restrict__ zrow,
    const float* __restrict__ cbias,
    float* __restrict__ out, int b0) {
  // xs[ri][wi][ci] : ri 0..3 -> x row h0*2-1+ri ; wi 0..129 -> w = wi-1 ; 32 ci
  __shared__ __align__(16) __hip_bfloat16 xs[4 * 130 * 32];   // 33,280 B
  // wbuf[kw][co][ci] : 3 x 128 x 32 (this block's co-half, one kh at a time)
  __shared__ __align__(16) __hip_bfloat16 wbuf[3 * 128 * 32]; // 24,576 B

  // XCD-aware swizzle (nwg = G*128, always % 8 == 0)
  int nwg = gridDim.x;
  int bid0 = blockIdx.x;
  int bid = (bid0 & 7) * (nwg >> 3) + (bid0 >> 3);

  int hp = bid & 63, coh = (bid >> 6) & 1, bp = bid >> 7;
  int b = b0 + bp;
  int h0 = hp * 2;

  int tid = threadIdx.x;
  int wid = tid >> 6, lane = tid & 63;
  int l15 = lane & 15, lh = lane >> 4;
  int row = wid >> 1;               // output row within pair (0/1)
  int w0 = (wid & 1) * 64;          // w half
  int lrow = lane >> 2;
  int sgx = (lane & 3) ^ (((1 + lrow) >> 1) & 3);  // x-stage source granule
  int sgw = (lane & 3) ^ ((lrow >> 1) & 3);        // w-stage source granule
  int asw = (l15 >> 1) & 3;                        // A-frag read swizzle

  // zero the w-pad columns (wi = 0 and wi = 129); never overwritten after
  if (tid < 256) {
    int ri = tid >> 6, which = (tid >> 5) & 1, ci = tid & 31;
    ((ushort*)xs)[ri * 4160 + (which ? 129 : 0) * 32 + ci] = 0;
  }

  // ---- precomputed offsets (elements) ----
  int a_base = l15 * 32 + (lh ^ asw) * 8;        // + kw*4096 + mf*512
  int b_base0 = (w0 + l15 + 0) * 32 + ((lh ^ (((l15 + 0) >> 1) & 3)) * 8);
  int b_base1 = (w0 + l15 + 1) * 32 + ((lh ^ (((l15 + 1) >> 1) & 3)) * 8);
  int b_base2 = (w0 + l15 + 2) * 32 + ((lh ^ (((l15 + 2) >> 1) & 3)) * 8);
  int xoff = lrow * 256 + sgx * 8;               // + wblk*4096 + c0
  int woff = (coh * 128 + lrow) * 256 + sgw * 8; // + kw*65536 + cblk*4096 + c0

  const __hip_bfloat16* xTb = xT + (size_t)bp * 128 * 128 * 256;
  const __hip_bfloat16* r0 = (h0 > 0)   ? xTb + (size_t)(h0 - 1) * 32768 : zrow;
  const __hip_bfloat16* r1 = xTb + (size_t)h0 * 32768;
  const __hip_bfloat16* r2 = xTb + (size_t)(h0 + 1) * 32768;
  const __hip_bfloat16* r3 = (h0 < 126) ? xTb + (size_t)(h0 + 2) * 32768 : zrow;

  f32x4 acc[8][4];
#pragma unroll
  for (int mf = 0; mf < 8; ++mf)
#pragma unroll
    for (int nf = 0; nf < 4; ++nf) acc[mf][nf] = (f32x4){0.f, 0.f, 0.f, 0.f};

  for (int cb8 = 0; cb8 < 8; ++cb8) {
    int c0 = cb8 * 32;
    __syncthreads();  // previous phase done reading xs/wbuf

    // stage x: 32 x (1KB gload16), 8/wave; rows h0-1..h0+2; ri compile-time
#pragma unroll
    for (int k = 0; k < 8; ++k) {
      const int ri = k >> 1;
      int wblk = (k & 1) * 4 + wid;
      const __hip_bfloat16* rp = (ri == 0) ? r0 : ((ri == 1) ? r1 : ((ri == 2) ? r2 : r3));
      gload16((const void*)(rp + wblk * 4096 + c0 + xoff),
              (void*)(xs + ri * 4160 + (1 + wblk * 16) * 32));
    }

    // stage W for kh, then compute; 3 kh phases
#pragma unroll 1
    for (int kh = 0; kh < 3; ++kh) {
      if (kh) __syncthreads();  // compute(kh-1) done reading wbuf
      const __hip_bfloat16* wtap =
          Weff + ((size_t)(b * 9 + kh * 3) << 16) + c0 + woff;
      // slot = k*4+wid -> kw = k>>1 compile-time, cblk = (k&1)*4+wid
#pragma unroll
      for (int k = 0; k < 6; ++k) {
        const int kw = k >> 1;
        int cblk = (k & 1) * 4 + wid;
        gload16((const void*)(wtap + kw * 65536 + cblk * 4096),
                (void*)(wbuf + kw * 4096 + cblk * 512));
      }
      __syncthreads();  // staging complete (syncthreads drains vmcnt)

#pragma unroll
      for (int kw = 0; kw < 3; ++kw) {
        int bb = (kw == 0) ? b_base0 : ((kw == 1) ? b_base1 : b_base2);
        bf16x8 af[8], bfr[4];
#pragma unroll
        for (int mf = 0; mf < 8; ++mf)
          af[mf] = *(const bf16x8*)&wbuf[kw * 4096 + a_base + mf * 512];
#pragma unroll
        for (int nf = 0; nf < 4; ++nf)
          bfr[nf] = *(const bf16x8*)&xs[(row + kh) * 4160 + bb + nf * 512];
#pragma unroll
        for (int mf = 0; mf < 8; ++mf)
#pragma unroll
          for (int nf = 0; nf < 4; ++nf)
            acc[mf][nf] = __builtin_amdgcn_mfma_f32_16x16x32_bf16(af[mf], bfr[nf],
                                                                  acc[mf][nf], 0, 0, 0);
      }
    }
  }

  // epilogue: D[m][n]: m(co) = (lane>>4)*4 + r, n(px) = lane&15
#pragma unroll
  for (int mf = 0; mf < 8; ++mf) {
    int cobase = coh * 128 + mf * 16 + lh * 4;
#pragma unroll
    for (int r = 0; r < 4; ++r) {
      int co = cobase + r;
      float bias = cbias[co];
      size_t obase = ((size_t)(b * 256 + co) * 128 + (h0 + row)) * 128 + w0 + l15;
#pragma unroll
      for (int nf = 0; nf < 4; ++nf) out[obase + nf * 16] = acc[mf][nf][r] + bias;
    }
  }
}

extern "C" void kernel_launch(void* const* d_in, const int* in_sizes, int n_in,
                              void* d_out, int out_size, void* d_ws, size_t ws_size,
                              hipStream_t stream) {
  const float* x      = (const float*)d_in[0];
  const float* wms    = (const float*)d_in[1];
  const float* conv_w = (const float*)d_in[2];
  const float* conv_b = (const float*)d_in[3];
  const float* e1w1   = (const float*)d_in[4];
  const float* e1b1   = (const float*)d_in[5];
  const float* e1w2   = (const float*)d_in[6];
  const float* e1b2   = (const float*)d_in[7];
  const float* e2w1   = (const float*)d_in[8];
  const float* e2b1   = (const float*)d_in[9];
  const float* e2w2   = (const float*)d_in[10];
  const float* e2b2   = (const float*)d_in[11];
  const float* A1     = (const float*)d_in[12];
  const float* A2     = (const float*)d_in[13];
  const float* loraB  = (const float*)d_in[14];
  float* out = (float*)d_out;

  uint8_t* ws = (uint8_t*)d_ws;
  __hip_bfloat16* zrow = (__hip_bfloat16*)(ws + OFF_ZROW);
  float* coff          = (float*)(ws + OFF_COFF);
  float* tmpS          = (float*)(ws + OFF_TMPS);
  __hip_bfloat16* Weff = (__hip_bfloat16*)(ws + OFF_WEFF);
  __hip_bfloat16* xT   = (__hip_bfloat16*)(ws + OFF_XT);

  // group size: how many samples' xT fit in ws
  int G = 16;
  while (G > 1 && (size_t)OFF_XT + (size_t)G * XT_PER_B > ws_size) G >>= 1;

  hipMemsetAsync(zrow, 0, 65536, stream);
  k_coff<<<32, 256, 0, stream>>>(wms, e1w1, e1b1, e1w2, e1b2, e2w1, e2b1, e2w2, e2b2, coff);
  k_tmps<<<256, 256, 0, stream>>>(coff, A1, A2, tmpS);
  k_weff<<<16 * 256, 256, 0, stream>>>(conv_w, loraB, tmpS, Weff);
  for (int g = 0; g < 16; g += G) {
    k_xt<<<G * 1024, 256, 0, stream>>>(x, xT, g);
    k_conv<<<G * 128, 256, 0, stream>>>(xT, Weff, zrow, conv_b, out, g);
  }
}

// Round 14
// 414.876 us; speedup vs baseline: 1.7473x; 1.0193x over previous
//
#include <hip/hip_runtime.h>
#include <hip/hip_bf16.h>
#include <stdint.h>

typedef __bf16 bf16x8 __attribute__((ext_vector_type(8)));
typedef float f32x4 __attribute__((ext_vector_type(4)));
typedef unsigned short ushort8v __attribute__((ext_vector_type(8)));

// Problem constants
#define NB    16
#define CIN   256
#define COUT  256
#define HH    128
#define WW    128

// ws layout (bytes)
#define OFF_ZROW  0u                    // 65536 zeroed page (one fake xT row)
#define OFF_COFF  (1u << 16)            // 2*16*256 f32 = 8 KB
#define OFF_TMPS  (1u << 17)            // 16*16*768 f32 = 768 KB
#define OFF_WEFF  (1u << 20)            // 16*9*256*256 bf16 = 18 MB
#define OFF_XT    (20u * 1024u * 1024u) // G * 8 MB bf16 channels-last x
#define XT_PER_B  (128u * 128u * 256u * 2u)

__device__ inline void gload16(const void* g, void* l) {
  __builtin_amdgcn_global_load_lds(
      (const __attribute__((address_space(1))) void*)g,
      (__attribute__((address_space(3))) void*)l, 16, 0, 0);
}

__device__ inline ushort f2bf(float f) {
  __hip_bfloat16 h = __float2bfloat16(f);
  union { __hip_bfloat16 b; ushort u; } cv;
  cv.b = h;
  return cv.u;
}

// ---------------- kernel 1: embed MLP -> coff[2][16][16][16] ----------------
__global__ void k_coff(const float* __restrict__ wms,
                       const float* __restrict__ w1a, const float* __restrict__ b1a,
                       const float* __restrict__ w2a, const float* __restrict__ b2a,
                       const float* __restrict__ w1b, const float* __restrict__ b1b,
                       const float* __restrict__ w2b, const float* __restrict__ b2b,
                       float* __restrict__ coff) {
  int br = blockIdx.x >> 4, b = blockIdx.x & 15;
  const float* w1 = br ? w1b : w1a;
  const float* b1 = br ? b1b : b1a;
  const float* w2 = br ? w2b : w2a;
  const float* b2 = br ? b2b : b2a;
  const float* v = wms + (br * 16 + b) * 32;
  __shared__ float h[128];
  int t = threadIdx.x;
  if (t < 128) {
    float a = b1[t];
#pragma unroll
    for (int i = 0; i < 32; ++i) a += w1[t * 32 + i] * v[i];
    h[t] = a >= 0.f ? a : 0.2f * a;
  }
  __syncthreads();
  float a = b2[t];
  for (int j = 0; j < 128; ++j) a += w2[t * 128 + j] * h[j];
  coff[(br * 16 + b) * 256 + t] = a;
}

// ------------- kernel 2a: tmpS[b][r][c] = coff1@A1 + coff2@A2 ---------------
__global__ void k_tmps(const float* __restrict__ coff,
                       const float* __restrict__ A1, const float* __restrict__ A2,
                       float* __restrict__ tmpS) {
  int b = blockIdx.x >> 4, r = blockIdx.x & 15;
  __shared__ float c1[16], c2[16];
  int t = threadIdx.x;
  if (t < 16) {
    c1[t] = coff[b * 256 + r * 16 + t];
    c2[t] = coff[(16 + b) * 256 + r * 16 + t];
  }
  __syncthreads();
  for (int c = t; c < 768; c += 256) {
    float s = 0.f;
#pragma unroll
    for (int q = 0; q < 16; ++q) s += c1[q] * A1[q * 768 + c] + c2[q] * A2[q * 768 + c];
    tmpS[(b * 16 + r) * 768 + c] = s;
  }
}

// ---- fused prep kernel: [0, nweff) -> Weff blocks ; [nweff, ...) -> xT ------
// weff: Weff[b][tt][co][ci] = conv_w + loraB @ tmpS (bf16); block = (b, co)
// xt:   x (f32, NCHW) -> xT (bf16, NHWC); block = (bp, h, cb)
// Independent workloads (weff: L2/VALU-bound, xt: HBM-bound) run CONCURRENTLY
// in one launch instead of serializing on the stream.
__global__ __launch_bounds__(256) void k_prep(
    const float* __restrict__ conv_w, const float* __restrict__ loraB,
    const float* __restrict__ tmpS, __hip_bfloat16* __restrict__ Weff,
    const float* __restrict__ x, __hip_bfloat16* __restrict__ xT,
    int b0, int nweff) {
  __shared__ ushort sbuf[32 * 132];  // 8448 ushort: union of both parts' needs
  int bid = blockIdx.x;
  int tid = threadIdx.x;

  if (bid < nweff) {
    // ---------------- weff part ----------------
    int co = bid & 255, b = bid >> 8;
    ushort* obuf = sbuf;                          // 2304 ushort
    float* Bs = (float*)(sbuf + 2304);            // 48 floats (4B-aligned)
    if (tid < 48) Bs[(tid >> 4) * 16 + (tid & 15)] =
        loraB[(co * 3 + (tid >> 4)) * 16 + (tid & 15)];
    __syncthreads();
    const float* T = tmpS + (size_t)b * 16 * 768;
    const float* W = conv_w + (size_t)co * 2304;
#pragma unroll
    for (int k = 0; k < 3; ++k) {
#pragma unroll
      for (int cc = 0; cc < 3; ++cc) {
        int c = cc * 256 + tid;
        float s = W[k * 768 + c];
        const float* Bk = Bs + k * 16;
#pragma unroll
        for (int r = 0; r < 16; ++r) s += Bk[r] * T[r * 768 + c];
        int f = k * 768 + c;  // local flat over (ci,kh,kw) for this co
        int ci = f / 9, tt = f - ci * 9;
        obuf[tt * 256 + ci] = f2bf(s);
      }
    }
    __syncthreads();
#pragma unroll
    for (int tt = 0; tt < 9; ++tt)
      ((ushort*)Weff)[((size_t)(b * 9 + tt) * 256 + co) * 256 + tid] =
          obuf[tt * 256 + tid];
  } else {
    // ---------------- xt part ----------------
    int xbid = bid - nweff;
    int cb = xbid & 7, h = (xbid >> 3) & 127, bp = xbid >> 10;
    int b = b0 + bp;
    ushort(*t)[132] = (ushort(*)[132])sbuf;
    int ci2 = tid >> 5, w4 = (tid & 31) * 4;
    const float* srcb = x + ((size_t)(b * 256 + cb * 32) * 128 + h) * 128;
#pragma unroll
    for (int k = 0; k < 4; ++k) {
      int c = ci2 + k * 8;
      float4 v = *(const float4*)(srcb + (size_t)c * 16384 + w4);
      ushort4 u;
      u.x = f2bf(v.x);
      u.y = f2bf(v.y);
      u.z = f2bf(v.z);
      u.w = f2bf(v.w);
      *(ushort4*)&t[c][w4] = u;
    }
    __syncthreads();
    int w = tid >> 1, hf = tid & 1;
    ushort8v o0, o1;
#pragma unroll
    for (int j = 0; j < 8; ++j) {
      o0[j] = t[hf * 16 + j][w];
      o1[j] = t[hf * 16 + 8 + j][w];
    }
    ushort* dst = (ushort*)xT + (size_t)bp * 128 * 128 * 256 +
                  ((size_t)h * 128 + w) * 256 + cb * 32 + hf * 16;
    *(ushort8v*)dst = o0;
    *(ushort8v*)(dst + 8) = o1;
  }
}

// ------------------- kernel 4: per-sample implicit-GEMM conv ------------------
// FROZEN at round-13 (best: 293 us, MfmaUtil 47.7%, 0 bank conflicts).
// 128co x 2rows x 128w block, 4 waves of 128co x 64w x 1row (acc 128 AGPR),
// 2 blocks/CU; granule swizzle g' = g ^ ((row>>1)&3) both sides.
__global__ __launch_bounds__(256, 2) void k_conv(
    const __hip_bfloat16* __restrict__ xT,
    const __hip_bfloat16* __restrict__ Weff,
    const __hip_bfloat16* __restrict__ zrow,
    const float* __restrict__ cbias,
    float* __restrict__ out, int b0) {
  // xs[ri][wi][ci] : ri 0..3 -> x row h0*2-1+ri ; wi 0..129 -> w = wi-1 ; 32 ci
  __shared__ __align__(16) __hip_bfloat16 xs[4 * 130 * 32];   // 33,280 B
  // wbuf[kw][co][ci] : 3 x 128 x 32 (this block's co-half, one kh at a time)
  __shared__ __align__(16) __hip_bfloat16 wbuf[3 * 128 * 32]; // 24,576 B

  // XCD-aware swizzle (nwg = G*128, always % 8 == 0)
  int nwg = gridDim.x;
  int bid0 = blockIdx.x;
  int bid = (bid0 & 7) * (nwg >> 3) + (bid0 >> 3);

  int hp = bid & 63, coh = (bid >> 6) & 1, bp = bid >> 7;
  int b = b0 + bp;
  int h0 = hp * 2;

  int tid = threadIdx.x;
  int wid = tid >> 6, lane = tid & 63;
  int l15 = lane & 15, lh = lane >> 4;
  int row = wid >> 1;               // output row within pair (0/1)
  int w0 = (wid & 1) * 64;          // w half
  int lrow = lane >> 2;
  int sgx = (lane & 3) ^ (((1 + lrow) >> 1) & 3);  // x-stage source granule
  int sgw = (lane & 3) ^ ((lrow >> 1) & 3);        // w-stage source granule
  int asw = (l15 >> 1) & 3;                        // A-frag read swizzle

  // zero the w-pad columns (wi = 0 and wi = 129); never overwritten after
  if (tid < 256) {
    int ri = tid >> 6, which = (tid >> 5) & 1, ci = tid & 31;
    ((ushort*)xs)[ri * 4160 + (which ? 129 : 0) * 32 + ci] = 0;
  }

  // ---- precomputed offsets (elements) ----
  int a_base = l15 * 32 + (lh ^ asw) * 8;        // + kw*4096 + mf*512
  int b_base0 = (w0 + l15 + 0) * 32 + ((lh ^ (((l15 + 0) >> 1) & 3)) * 8);
  int b_base1 = (w0 + l15 + 1) * 32 + ((lh ^ (((l15 + 1) >> 1) & 3)) * 8);
  int b_base2 = (w0 + l15 + 2) * 32 + ((lh ^ (((l15 + 2) >> 1) & 3)) * 8);
  int xoff = lrow * 256 + sgx * 8;               // + wblk*4096 + c0
  int woff = (coh * 128 + lrow) * 256 + sgw * 8; // + kw*65536 + cblk*4096 + c0

  const __hip_bfloat16* xTb = xT + (size_t)bp * 128 * 128 * 256;
  const __hip_bfloat16* r0 = (h0 > 0)   ? xTb + (size_t)(h0 - 1) * 32768 : zrow;
  const __hip_bfloat16* r1 = xTb + (size_t)h0 * 32768;
  const __hip_bfloat16* r2 = xTb + (size_t)(h0 + 1) * 32768;
  const __hip_bfloat16* r3 = (h0 < 126) ? xTb + (size_t)(h0 + 2) * 32768 : zrow;

  f32x4 acc[8][4];
#pragma unroll
  for (int mf = 0; mf < 8; ++mf)
#pragma unroll
    for (int nf = 0; nf < 4; ++nf) acc[mf][nf] = (f32x4){0.f, 0.f, 0.f, 0.f};

  for (int cb8 = 0; cb8 < 8; ++cb8) {
    int c0 = cb8 * 32;
    __syncthreads();  // previous phase done reading xs/wbuf

    // stage x: 32 x (1KB gload16), 8/wave; rows h0-1..h0+2; ri compile-time
#pragma unroll
    for (int k = 0; k < 8; ++k) {
      const int ri = k >> 1;
      int wblk = (k & 1) * 4 + wid;
      const __hip_bfloat16* rp = (ri == 0) ? r0 : ((ri == 1) ? r1 : ((ri == 2) ? r2 : r3));
      gload16((const void*)(rp + wblk * 4096 + c0 + xoff),
              (void*)(xs + ri * 4160 + (1 + wblk * 16) * 32));
    }

    // stage W for kh, then compute; 3 kh phases
#pragma unroll 1
    for (int kh = 0; kh < 3; ++kh) {
      if (kh) __syncthreads();  // compute(kh-1) done reading wbuf
      const __hip_bfloat16* wtap =
          Weff + ((size_t)(b * 9 + kh * 3) << 16) + c0 + woff;
      // slot = k*4+wid -> kw = k>>1 compile-time, cblk = (k&1)*4+wid
#pragma unroll
      for (int k = 0; k < 6; ++k) {
        const int kw = k >> 1;
        int cblk = (k & 1) * 4 + wid;
        gload16((const void*)(wtap + kw * 65536 + cblk * 4096),
                (void*)(wbuf + kw * 4096 + cblk * 512));
      }
      __syncthreads();  // staging complete (syncthreads drains vmcnt)

#pragma unroll
      for (int kw = 0; kw < 3; ++kw) {
        int bb = (kw == 0) ? b_base0 : ((kw == 1) ? b_base1 : b_base2);
        bf16x8 af[8], bfr[4];
#pragma unroll
        for (int mf = 0; mf < 8; ++mf)
          af[mf] = *(const bf16x8*)&wbuf[kw * 4096 + a_base + mf * 512];
#pragma unroll
        for (int nf = 0; nf < 4; ++nf)
          bfr[nf] = *(const bf16x8*)&xs[(row + kh) * 4160 + bb + nf * 512];
#pragma unroll
        for (int mf = 0; mf < 8; ++mf)
#pragma unroll
          for (int nf = 0; nf < 4; ++nf)
            acc[mf][nf] = __builtin_amdgcn_mfma_f32_16x16x32_bf16(af[mf], bfr[nf],
                                                                  acc[mf][nf], 0, 0, 0);
      }
    }
  }

  // epilogue: D[m][n]: m(co) = (lane>>4)*4 + r, n(px) = lane&15
#pragma unroll
  for (int mf = 0; mf < 8; ++mf) {
    int cobase = coh * 128 + mf * 16 + lh * 4;
#pragma unroll
    for (int r = 0; r < 4; ++r) {
      int co = cobase + r;
      float bias = cbias[co];
      size_t obase = ((size_t)(b * 256 + co) * 128 + (h0 + row)) * 128 + w0 + l15;
#pragma unroll
      for (int nf = 0; nf < 4; ++nf) out[obase + nf * 16] = acc[mf][nf][r] + bias;
    }
  }
}

extern "C" void kernel_launch(void* const* d_in, const int* in_sizes, int n_in,
                              void* d_out, int out_size, void* d_ws, size_t ws_size,
                              hipStream_t stream) {
  const float* x      = (const float*)d_in[0];
  const float* wms    = (const float*)d_in[1];
  const float* conv_w = (const float*)d_in[2];
  const float* conv_b = (const float*)d_in[3];
  const float* e1w1   = (const float*)d_in[4];
  const float* e1b1   = (const float*)d_in[5];
  const float* e1w2   = (const float*)d_in[6];
  const float* e1b2   = (const float*)d_in[7];
  const float* e2w1   = (const float*)d_in[8];
  const float* e2b1   = (const float*)d_in[9];
  const float* e2w2   = (const float*)d_in[10];
  const float* e2b2   = (const float*)d_in[11];
  const float* A1     = (const float*)d_in[12];
  const float* A2     = (const float*)d_in[13];
  const float* loraB  = (const float*)d_in[14];
  float* out = (float*)d_out;

  uint8_t* ws = (uint8_t*)d_ws;
  __hip_bfloat16* zrow = (__hip_bfloat16*)(ws + OFF_ZROW);
  float* coff          = (float*)(ws + OFF_COFF);
  float* tmpS          = (float*)(ws + OFF_TMPS);
  __hip_bfloat16* Weff = (__hip_bfloat16*)(ws + OFF_WEFF);
  __hip_bfloat16* xT   = (__hip_bfloat16*)(ws + OFF_XT);

  // group size: how many samples' xT fit in ws
  int G = 16;
  while (G > 1 && (size_t)OFF_XT + (size_t)G * XT_PER_B > ws_size) G >>= 1;

  hipMemsetAsync(zrow, 0, 65536, stream);
  k_coff<<<32, 256, 0, stream>>>(wms, e1w1, e1b1, e1w2, e1b2, e2w1, e2b1, e2w2, e2b2, coff);
  k_tmps<<<256, 256, 0, stream>>>(coff, A1, A2, tmpS);
  for (int g = 0; g < 16; g += G) {
    int nweff = (g == 0) ? 16 * 256 : 0;  // weff work only in first group
    k_prep<<<nweff + G * 1024, 256, 0, stream>>>(conv_w, loraB, tmpS, Weff,
                                                 x, xT, g, nweff);
    k_conv<<<G * 128, 256, 0, stream>>>(xT, Weff, zrow, conv_b, out, g);
  }
}

// Round 15
// 406.392 us; speedup vs baseline: 1.7838x; 1.0209x over previous
//
#include <hip/hip_runtime.h>
#include <hip/hip_bf16.h>
#include <stdint.h>

typedef __bf16 bf16x8 __attribute__((ext_vector_type(8)));
typedef float f32x4 __attribute__((ext_vector_type(4)));
typedef unsigned short ushort8v __attribute__((ext_vector_type(8)));

// Problem constants
#define NB    16
#define CIN   256
#define COUT  256
#define HH    128
#define WW    128

// ws layout (bytes)
#define OFF_ZROW  0u                    // 65536 zeroed page (one fake xT row)
#define OFF_COFF  (1u << 16)            // 2*16*256 f32 = 8 KB
#define OFF_TMPS  (1u << 17)            // 16*16*768 f32 = 768 KB
#define OFF_WEFF  (1u << 20)            // 16*9*256*256 bf16 = 18 MB
#define OFF_XT    (20u * 1024u * 1024u) // per-slot 8 MB bf16 channels-last x
#define XT_PER_B  (128u * 128u * 256u * 2u)

#define CONV_LDS_BYTES (4 * 130 * 32 * 2 + 3 * 128 * 32 * 2)  // 57,856

__device__ inline void gload16(const void* g, void* l) {
  __builtin_amdgcn_global_load_lds(
      (const __attribute__((address_space(1))) void*)g,
      (__attribute__((address_space(3))) void*)l, 16, 0, 0);
}

__device__ inline ushort f2bf(float f) {
  __hip_bfloat16 h = __float2bfloat16(f);
  union { __hip_bfloat16 b; ushort u; } cv;
  cv.b = h;
  return cv.u;
}

// ---------------- kernel 1: embed MLP -> coff[2][16][16][16] ----------------
__global__ void k_coff(const float* __restrict__ wms,
                       const float* __restrict__ w1a, const float* __restrict__ b1a,
                       const float* __restrict__ w2a, const float* __restrict__ b2a,
                       const float* __restrict__ w1b, const float* __restrict__ b1b,
                       const float* __restrict__ w2b, const float* __restrict__ b2b,
                       float* __restrict__ coff) {
  int br = blockIdx.x >> 4, b = blockIdx.x & 15;
  const float* w1 = br ? w1b : w1a;
  const float* b1 = br ? b1b : b1a;
  const float* w2 = br ? w2b : w2a;
  const float* b2 = br ? b2b : b2a;
  const float* v = wms + (br * 16 + b) * 32;
  __shared__ float h[128];
  int t = threadIdx.x;
  if (t < 128) {
    float a = b1[t];
#pragma unroll
    for (int i = 0; i < 32; ++i) a += w1[t * 32 + i] * v[i];
    h[t] = a >= 0.f ? a : 0.2f * a;
  }
  __syncthreads();
  float a = b2[t];
  for (int j = 0; j < 128; ++j) a += w2[t * 128 + j] * h[j];
  coff[(br * 16 + b) * 256 + t] = a;
}

// ------------- kernel 2a: tmpS[b][r][c] = coff1@A1 + coff2@A2 ---------------
__global__ void k_tmps(const float* __restrict__ coff,
                       const float* __restrict__ A1, const float* __restrict__ A2,
                       float* __restrict__ tmpS) {
  int b = blockIdx.x >> 4, r = blockIdx.x & 15;
  __shared__ float c1[16], c2[16];
  int t = threadIdx.x;
  if (t < 16) {
    c1[t] = coff[b * 256 + r * 16 + t];
    c2[t] = coff[(16 + b) * 256 + r * 16 + t];
  }
  __syncthreads();
  for (int c = t; c < 768; c += 256) {
    float s = 0.f;
#pragma unroll
    for (int q = 0; q < 16; ++q) s += c1[q] * A1[q * 768 + c] + c2[q] * A2[q * 768 + c];
    tmpS[(b * 16 + r) * 768 + c] = s;
  }
}

// --------------------------- device block bodies -----------------------------

// weff: Weff[b][tt][co][ci] = conv_w + loraB @ tmpS (bf16); block = (b, co)
__device__ __forceinline__ void weff_block(
    int bid, ushort* sbuf, const float* __restrict__ conv_w,
    const float* __restrict__ loraB, const float* __restrict__ tmpS,
    __hip_bfloat16* __restrict__ Weff) {
  int co = bid & 255, b = bid >> 8;
  int tid = threadIdx.x;
  ushort* obuf = sbuf;                 // 2304 ushort
  float* Bs = (float*)(sbuf + 2304);   // 48 floats
  if (tid < 48)
    Bs[(tid >> 4) * 16 + (tid & 15)] = loraB[(co * 3 + (tid >> 4)) * 16 + (tid & 15)];
  __syncthreads();
  const float* T = tmpS + (size_t)b * 16 * 768;
  const float* W = conv_w + (size_t)co * 2304;
#pragma unroll
  for (int k = 0; k < 3; ++k) {
#pragma unroll
    for (int cc = 0; cc < 3; ++cc) {
      int c = cc * 256 + tid;
      float s = W[k * 768 + c];
      const float* Bk = Bs + k * 16;
#pragma unroll
      for (int r = 0; r < 16; ++r) s += Bk[r] * T[r * 768 + c];
      int f = k * 768 + c;
      int ci = f / 9, tt = f - ci * 9;
      obuf[tt * 256 + ci] = f2bf(s);
    }
  }
  __syncthreads();
#pragma unroll
  for (int tt = 0; tt < 9; ++tt)
    ((ushort*)Weff)[((size_t)(b * 9 + tt) * 256 + co) * 256 + tid] = obuf[tt * 256 + tid];
}

// xt: x (f32, NCHW sample b0+bp) -> xT slot (xslot0+bp) (bf16, NHWC)
__device__ __forceinline__ void xt_block(
    int xbid, int b0, int xslot0, ushort* sbuf,
    const float* __restrict__ x, __hip_bfloat16* __restrict__ xT) {
  int cb = xbid & 7, h = (xbid >> 3) & 127, bp = xbid >> 10;
  int b = b0 + bp;
  int tid = threadIdx.x;
  ushort(*t)[132] = (ushort(*)[132])sbuf;
  int ci2 = tid >> 5, w4 = (tid & 31) * 4;
  const float* srcb = x + ((size_t)(b * 256 + cb * 32) * 128 + h) * 128;
#pragma unroll
  for (int k = 0; k < 4; ++k) {
    int c = ci2 + k * 8;
    float4 v = *(const float4*)(srcb + (size_t)c * 16384 + w4);
    ushort4 u;
    u.x = f2bf(v.x);
    u.y = f2bf(v.y);
    u.z = f2bf(v.z);
    u.w = f2bf(v.w);
    *(ushort4*)&t[c][w4] = u;
  }
  __syncthreads();
  int w = tid >> 1, hf = tid & 1;
  ushort8v o0, o1;
#pragma unroll
  for (int j = 0; j < 8; ++j) {
    o0[j] = t[hf * 16 + j][w];
    o1[j] = t[hf * 16 + 8 + j][w];
  }
  ushort* dst = (ushort*)xT + (size_t)(xslot0 + bp) * 128 * 128 * 256 +
                ((size_t)h * 128 + w) * 256 + cb * 32 + hf * 16;
  *(ushort8v*)dst = o0;
  *(ushort8v*)(dst + 8) = o1;
}

// conv: FROZEN round-13 schedule (293 us, MfmaUtil 47.7%, 0 bank conflicts).
// 128co x 2rows x 128w block, 4 waves of 128co x 64w x 1row (acc 128 AGPR),
// granule swizzle g' = g ^ ((row>>1)&3) both sides. nwg = conv grid (for XCD
// swizzle), b0 = sample base, xslot0 = xT slot base.
__device__ __forceinline__ void conv_block(
    int bid0, int nwg, int b0, int xslot0,
    __hip_bfloat16* xs, __hip_bfloat16* wbuf,
    const __hip_bfloat16* __restrict__ xT,
    const __hip_bfloat16* __restrict__ Weff,
    const __hip_bfloat16* __restrict__ zrow,
    const float* __restrict__ cbias, float* __restrict__ out) {
  int bid = (bid0 & 7) * (nwg >> 3) + (bid0 >> 3);  // XCD swizzle (nwg%8==0)

  int hp = bid & 63, coh = (bid >> 6) & 1, bp = bid >> 7;
  int b = b0 + bp;
  int h0 = hp * 2;

  int tid = threadIdx.x;
  int wid = tid >> 6, lane = tid & 63;
  int l15 = lane & 15, lh = lane >> 4;
  int row = wid >> 1;               // output row within pair (0/1)
  int w0 = (wid & 1) * 64;          // w half
  int lrow = lane >> 2;
  int sgx = (lane & 3) ^ (((1 + lrow) >> 1) & 3);  // x-stage source granule
  int sgw = (lane & 3) ^ ((lrow >> 1) & 3);        // w-stage source granule
  int asw = (l15 >> 1) & 3;                        // A-frag read swizzle

  // zero the w-pad columns (wi = 0 and wi = 129); never overwritten after
  {
    int ri = tid >> 6, which = (tid >> 5) & 1, ci = tid & 31;
    ((ushort*)xs)[ri * 4160 + (which ? 129 : 0) * 32 + ci] = 0;
  }

  // ---- precomputed offsets (elements) ----
  int a_base = l15 * 32 + (lh ^ asw) * 8;        // + kw*4096 + mf*512
  int b_base0 = (w0 + l15 + 0) * 32 + ((lh ^ (((l15 + 0) >> 1) & 3)) * 8);
  int b_base1 = (w0 + l15 + 1) * 32 + ((lh ^ (((l15 + 1) >> 1) & 3)) * 8);
  int b_base2 = (w0 + l15 + 2) * 32 + ((lh ^ (((l15 + 2) >> 1) & 3)) * 8);
  int xoff = lrow * 256 + sgx * 8;               // + wblk*4096 + c0
  int woff = (coh * 128 + lrow) * 256 + sgw * 8; // + kw*65536 + cblk*4096 + c0

  const __hip_bfloat16* xTb = xT + (size_t)(xslot0 + bp) * 128 * 128 * 256;
  const __hip_bfloat16* r0 = (h0 > 0)   ? xTb + (size_t)(h0 - 1) * 32768 : zrow;
  const __hip_bfloat16* r1 = xTb + (size_t)h0 * 32768;
  const __hip_bfloat16* r2 = xTb + (size_t)(h0 + 1) * 32768;
  const __hip_bfloat16* r3 = (h0 < 126) ? xTb + (size_t)(h0 + 2) * 32768 : zrow;

  f32x4 acc[8][4];
#pragma unroll
  for (int mf = 0; mf < 8; ++mf)
#pragma unroll
    for (int nf = 0; nf < 4; ++nf) acc[mf][nf] = (f32x4){0.f, 0.f, 0.f, 0.f};

  for (int cb8 = 0; cb8 < 8; ++cb8) {
    int c0 = cb8 * 32;
    __syncthreads();  // previous phase done reading xs/wbuf

    // stage x: 32 x (1KB gload16), 8/wave; rows h0-1..h0+2; ri compile-time
#pragma unroll
    for (int k = 0; k < 8; ++k) {
      const int ri = k >> 1;
      int wblk = (k & 1) * 4 + wid;
      const __hip_bfloat16* rp = (ri == 0) ? r0 : ((ri == 1) ? r1 : ((ri == 2) ? r2 : r3));
      gload16((const void*)(rp + wblk * 4096 + c0 + xoff),
              (void*)(xs + ri * 4160 + (1 + wblk * 16) * 32));
    }

    // stage W for kh, then compute; 3 kh phases
#pragma unroll 1
    for (int kh = 0; kh < 3; ++kh) {
      if (kh) __syncthreads();  // compute(kh-1) done reading wbuf
      const __hip_bfloat16* wtap =
          Weff + ((size_t)(b * 9 + kh * 3) << 16) + c0 + woff;
#pragma unroll
      for (int k = 0; k < 6; ++k) {
        const int kw = k >> 1;
        int cblk = (k & 1) * 4 + wid;
        gload16((const void*)(wtap + kw * 65536 + cblk * 4096),
                (void*)(wbuf + kw * 4096 + cblk * 512));
      }
      __syncthreads();  // staging complete (syncthreads drains vmcnt)

#pragma unroll
      for (int kw = 0; kw < 3; ++kw) {
        int bb = (kw == 0) ? b_base0 : ((kw == 1) ? b_base1 : b_base2);
        bf16x8 af[8], bfr[4];
#pragma unroll
        for (int mf = 0; mf < 8; ++mf)
          af[mf] = *(const bf16x8*)&wbuf[kw * 4096 + a_base + mf * 512];
#pragma unroll
        for (int nf = 0; nf < 4; ++nf)
          bfr[nf] = *(const bf16x8*)&xs[(row + kh) * 4160 + bb + nf * 512];
#pragma unroll
        for (int mf = 0; mf < 8; ++mf)
#pragma unroll
          for (int nf = 0; nf < 4; ++nf)
            acc[mf][nf] = __builtin_amdgcn_mfma_f32_16x16x32_bf16(af[mf], bfr[nf],
                                                                  acc[mf][nf], 0, 0, 0);
      }
    }
  }

  // epilogue: D[m][n]: m(co) = (lane>>4)*4 + r, n(px) = lane&15
#pragma unroll
  for (int mf = 0; mf < 8; ++mf) {
    int cobase = coh * 128 + mf * 16 + lh * 4;
#pragma unroll
    for (int r = 0; r < 4; ++r) {
      int co = cobase + r;
      float bias = cbias[co];
      size_t obase = ((size_t)(b * 256 + co) * 128 + (h0 + row)) * 128 + w0 + l15;
#pragma unroll
      for (int nf = 0; nf < 4; ++nf) out[obase + nf * 16] = acc[mf][nf][r] + bias;
    }
  }
}

// ------------------------------- kernels -------------------------------------

// prep: [0, nweff) -> weff blocks ; rest -> xt blocks
__global__ __launch_bounds__(256) void k_prep(
    const float* __restrict__ conv_w, const float* __restrict__ loraB,
    const float* __restrict__ tmpS, __hip_bfloat16* __restrict__ Weff,
    const float* __restrict__ x, __hip_bfloat16* __restrict__ xT,
    int b0, int xslot0, int nweff) {
  __shared__ __align__(16) ushort sbuf[32 * 132];
  int bid = blockIdx.x;
  if (bid < nweff)
    weff_block(bid, sbuf, conv_w, loraB, tmpS, Weff);
  else
    xt_block(bid - nweff, b0, xslot0, sbuf, x, xT);
}

// mix: [0, nconv) -> conv(samples b0c..) ; rest -> xt(samples b0x..)
// The two halves touch disjoint data (conv reads xT slots xs0c.., xt writes
// slots xs0x..) -> no ordering requirement; xt blocks backfill CUs as conv
// generations retire, hiding the xt HBM time under conv compute.
__global__ __launch_bounds__(256, 2) void k_mix(
    const __hip_bfloat16* __restrict__ xT_c, __hip_bfloat16* __restrict__ xT_w,
    const __hip_bfloat16* __restrict__ Weff,
    const __hip_bfloat16* __restrict__ zrow, const float* __restrict__ cbias,
    float* __restrict__ out, const float* __restrict__ x,
    int nconv, int b0c, int xs0c, int b0x, int xs0x) {
  __shared__ __align__(16) char smem[CONV_LDS_BYTES];
  int bid = blockIdx.x;
  if (bid < nconv)
    conv_block(bid, nconv, b0c, xs0c, (__hip_bfloat16*)smem,
               (__hip_bfloat16*)(smem + 33280), xT_c, Weff, zrow, cbias, out);
  else
    xt_block(bid - nconv, b0x, xs0x, (ushort*)smem, x, xT_w);
}

__global__ __launch_bounds__(256, 2) void k_conv(
    const __hip_bfloat16* __restrict__ xT,
    const __hip_bfloat16* __restrict__ Weff,
    const __hip_bfloat16* __restrict__ zrow,
    const float* __restrict__ cbias, float* __restrict__ out,
    int b0, int xslot0) {
  __shared__ __align__(16) char smem[CONV_LDS_BYTES];
  conv_block(blockIdx.x, gridDim.x, b0, xslot0, (__hip_bfloat16*)smem,
             (__hip_bfloat16*)(smem + 33280), xT, Weff, zrow, cbias, out);
}

extern "C" void kernel_launch(void* const* d_in, const int* in_sizes, int n_in,
                              void* d_out, int out_size, void* d_ws, size_t ws_size,
                              hipStream_t stream) {
  const float* x      = (const float*)d_in[0];
  const float* wms    = (const float*)d_in[1];
  const float* conv_w = (const float*)d_in[2];
  const float* conv_b = (const float*)d_in[3];
  const float* e1w1   = (const float*)d_in[4];
  const float* e1b1   = (const float*)d_in[5];
  const float* e1w2   = (const float*)d_in[6];
  const float* e1b2   = (const float*)d_in[7];
  const float* e2w1   = (const float*)d_in[8];
  const float* e2b1   = (const float*)d_in[9];
  const float* e2w2   = (const float*)d_in[10];
  const float* e2b2   = (const float*)d_in[11];
  const float* A1     = (const float*)d_in[12];
  const float* A2     = (const float*)d_in[13];
  const float* loraB  = (const float*)d_in[14];
  float* out = (float*)d_out;

  uint8_t* ws = (uint8_t*)d_ws;
  __hip_bfloat16* zrow = (__hip_bfloat16*)(ws + OFF_ZROW);
  float* coff          = (float*)(ws + OFF_COFF);
  float* tmpS          = (float*)(ws + OFF_TMPS);
  __hip_bfloat16* Weff = (__hip_bfloat16*)(ws + OFF_WEFF);
  __hip_bfloat16* xT   = (__hip_bfloat16*)(ws + OFF_XT);

  // group size: how many samples' xT fit in ws
  int G = 16;
  while (G > 1 && (size_t)OFF_XT + (size_t)G * XT_PER_B > ws_size) G >>= 1;

  hipMemsetAsync(zrow, 0, 65536, stream);
  k_coff<<<32, 256, 0, stream>>>(wms, e1w1, e1b1, e1w2, e1b2, e2w1, e2b1, e2w2, e2b2, coff);
  k_tmps<<<256, 256, 0, stream>>>(coff, A1, A2, tmpS);

  if (G == 16) {
    // 3-stage software pipeline over two half-batches:
    //   A: weff + xt(0-7)   B: conv(0-7) || xt(8-15)   C: conv(8-15)
    k_prep<<<4096 + 8 * 1024, 256, 0, stream>>>(conv_w, loraB, tmpS, Weff,
                                                x, xT, 0, 0, 4096);
    k_mix<<<8 * 128 + 8 * 1024, 256, 0, stream>>>(xT, xT, Weff, zrow, conv_b,
                                                  out, x, 8 * 128, 0, 0, 8, 8);
    k_conv<<<8 * 128, 256, 0, stream>>>(xT, Weff, zrow, conv_b, out, 8, 8);
  } else {
    for (int g = 0; g < 16; g += G) {
      int nweff = (g == 0) ? 4096 : 0;
      k_prep<<<nweff + G * 1024, 256, 0, stream>>>(conv_w, loraB, tmpS, Weff,
                                                   x, xT, g, 0, nweff);
      k_conv<<<G * 128, 256, 0, stream>>>(xT, Weff, zrow, conv_b, out, g, 0);
    }
  }
}